// Round 1
// baseline (725.743 us; speedup 1.0000x reference)
//
#include <hip/hip_runtime.h>

typedef unsigned short u16;
typedef u16   u16x8  __attribute__((ext_vector_type(8)));
typedef short short8 __attribute__((ext_vector_type(8)));
typedef float floatx4 __attribute__((ext_vector_type(4)));
typedef float f4     __attribute__((ext_vector_type(4)));

#define BB 8
#define NN 4096
#define CC 384

__device__ __forceinline__ u16 f2bf(float f){
  unsigned u = __float_as_uint(f);
  u += 0x7FFFu + ((u >> 16) & 1u);   // round-to-nearest-even
  return (u16)(u >> 16);
}
__device__ __forceinline__ float bf2f(u16 u){ return __uint_as_float(((unsigned)u) << 16); }

// ---------------- Kernel 1: depthwise conv 3x3 + LayerNorm + GELU(erf) + residual -> xa (f32) ----
__global__ __launch_bounds__(384) void k_conv_ln_gelu(
    const float* __restrict__ x, const float* __restrict__ w_sr, const float* __restrict__ b_sr,
    const float* __restrict__ ln_g, const float* __restrict__ ln_b, float* __restrict__ xa)
{
  const int pix = blockIdx.x;            // b*4096 + n
  const int b = pix >> 12, n = pix & 4095;
  const int hh = n >> 6, ww = n & 63;
  const int c = threadIdx.x;

  float wgt[9];
#pragma unroll
  for (int i = 0; i < 9; i++) wgt[i] = w_sr[c * 9 + i];

  float acc = b_sr[c];
#pragma unroll
  for (int kh = 0; kh < 3; kh++) {
    int y = hh + kh - 1;
    if ((unsigned)y >= 64u) continue;
#pragma unroll
    for (int kw = 0; kw < 3; kw++) {
      int xx = ww + kw - 1;
      if ((unsigned)xx >= 64u) continue;
      acc += x[(((b << 12) + (y << 6) + xx) * CC) + c] * wgt[kh * 3 + kw];
    }
  }

  float s1 = acc, s2 = acc * acc;
#pragma unroll
  for (int o = 32; o > 0; o >>= 1) { s1 += __shfl_down(s1, o); s2 += __shfl_down(s2, o); }
  __shared__ float ls1[6], ls2[6], mb[2];
  const int wid = threadIdx.x >> 6, lane = threadIdx.x & 63;
  if (lane == 0) { ls1[wid] = s1; ls2[wid] = s2; }
  __syncthreads();
  if (threadIdx.x == 0) {
    float a = 0.f, q = 0.f;
#pragma unroll
    for (int i = 0; i < 6; i++) { a += ls1[i]; q += ls2[i]; }
    float mean = a * (1.0f / CC);
    float var  = q * (1.0f / CC) - mean * mean;
    mb[0] = mean; mb[1] = rsqrtf(var + 1e-5f);
  }
  __syncthreads();
  float xn = (acc - mb[0]) * mb[1] * ln_g[c] + ln_b[c];
  float g  = 0.5f * xn * (1.0f + erff(xn * 0.70710678118654752f));
  xa[pix * CC + c] = x[pix * CC + c] + g;
}

// ---------------- Kernel 2: fused k|v GEMM + register k-softmax + MFMA ctx ------------------------
// grid (128 rowtiles of 256, 8 heads), block 256. ctx[bh,48,48] += ksm^T @ v (MFMA, 48x48x256)
__global__ __launch_bounds__(256) void k_kvctx(
    const float* __restrict__ xa, const float* __restrict__ wqkv, float* __restrict__ ctx)
{
  const int rt = blockIdx.x, h = blockIdx.y;
  const int n0 = rt << 8;
  const int bh = ((rt >> 4) << 3) + h;
  const int tid = threadIdx.x;
  const int wv = tid >> 6, lane = tid & 63, l15 = lane & 15, quad = lane >> 4;

  __shared__ __attribute__((aligned(16))) char smem[50688];
  u16 (*lA)[72]   = (u16(*)[72])smem;             // 256 x 72  (xa rows, k-chunk) bf16
  u16 (*lW)[72]   = (u16(*)[72])(smem + 36864);   // 96  x 72  (w cols transposed) bf16
  u16 (*lkT)[264] = (u16(*)[264])smem;            // 48 x 264  (ksm transposed: [d][r]) bf16
  u16 (*lvT)[264] = (u16(*)[264])(smem + 25344);  // 48 x 264  (v   transposed: [e][r]) bf16
  float (*pctx)[2304] = (float(*)[2304])smem;     // 4 x 2304  per-wave partial ctx

  floatx4 acc[24];
  const floatx4 z = {0.f, 0.f, 0.f, 0.f};
#pragma unroll
  for (int i = 0; i < 24; i++) acc[i] = z;

  for (int k0 = 0; k0 < 384; k0 += 64) {
    __syncthreads();
    // stage A: 256 rows x 64 k (f32 -> bf16)
#pragma unroll
    for (int i = 0; i < 16; i++) {
      int idx = tid + (i << 8);               // 0..4095
      int r = idx >> 4, c4 = (idx & 15) << 2;
      f4 v = *(const f4*)(xa + (size_t)(n0 + r) * 384 + k0 + c4);
#pragma unroll
      for (int j = 0; j < 4; j++) lA[r][c4 + j] = f2bf(v[j]);
    }
    // stage W: 64 k-rows x 96 cols (k|v of head h), transposed (f32 -> bf16)
#pragma unroll
    for (int i = 0; i < 6; i++) {
      int idx = tid + (i << 8);               // 0..1535
      int r = idx / 24, g = idx % 24;
      int colbase = (g < 12) ? (384 + h * 48 + (g << 2)) : (768 + h * 48 + ((g - 12) << 2));
      f4 v = *(const f4*)(wqkv + (size_t)(k0 + r) * 1152 + colbase);
      int cb = g << 2;
#pragma unroll
      for (int j = 0; j < 4; j++) lW[cb + j][r] = f2bf(v[j]);
    }
    __syncthreads();
#pragma unroll
    for (int rt4 = 0; rt4 < 4; rt4++) {
      int m = (wv << 6) + (rt4 << 4) + l15;
#pragma unroll
      for (int kk = 0; kk < 2; kk++) {
        short8 af = *(const short8*)&lA[m][(kk << 5) + (quad << 3)];
#pragma unroll
        for (int ct = 0; ct < 6; ct++) {
          short8 bf = *(const short8*)&lW[(ct << 4) + l15][(kk << 5) + (quad << 3)];
          acc[rt4 * 6 + ct] = __builtin_amdgcn_mfma_f32_16x16x32_bf16(af, bf, acc[rt4 * 6 + ct], 0, 0, 0);
        }
      }
    }
  }

  // ---- register softmax over the 48 k-columns of each row ----
  // row (n) of C = (wv<<6)+(rt4<<4)+(quad<<2)+rr; its 48 k-cols (ct=0..2) live across the
  // 16 l15-lanes of the same quad group -> shfl_xor masks 8,4,2,1 reduce exactly those lanes.
#pragma unroll
  for (int rt4 = 0; rt4 < 4; rt4++) {
#pragma unroll
    for (int rr = 0; rr < 4; rr++) {
      float x0 = acc[rt4 * 6 + 0][rr];
      float x1 = acc[rt4 * 6 + 1][rr];
      float x2 = acc[rt4 * 6 + 2][rr];
      float m = fmaxf(fmaxf(x0, x1), x2);
#pragma unroll
      for (int o = 8; o >= 1; o >>= 1) m = fmaxf(m, __shfl_xor(m, o));
      float e0 = expf(x0 - m), e1 = expf(x1 - m), e2 = expf(x2 - m);
      float s = e0 + e1 + e2;
#pragma unroll
      for (int o = 8; o >= 1; o >>= 1) s += __shfl_xor(s, o);
      float inv = 1.0f / s;
      acc[rt4 * 6 + 0][rr] = e0 * inv;
      acc[rt4 * 6 + 1][rr] = e1 * inv;
      acc[rt4 * 6 + 2][rr] = e2 * inv;
    }
  }

  __syncthreads();   // all waves done reading lA/lW; smem reused as lkT/lvT

  // ---- store ksm^T and v^T (bf16, r-contiguous rows) for the ctx MFMA ----
#pragma unroll
  for (int rt4 = 0; rt4 < 4; rt4++) {
    int rowb = (wv << 6) + (rt4 << 4) + (quad << 2);
#pragma unroll
    for (int ct = 0; ct < 6; ct++) {
      int col = (ct << 4) + l15;
      u16 (*dst)[264] = (ct < 3) ? lkT : lvT;
      int c = (ct < 3) ? col : (col - 48);
#pragma unroll
      for (int rp = 0; rp < 2; rp++) {
        unsigned lo = f2bf(acc[rt4 * 6 + ct][(rp << 1) + 0]);
        unsigned hi = f2bf(acc[rt4 * 6 + ct][(rp << 1) + 1]);
        *(unsigned*)&dst[c][rowb + (rp << 1)] = lo | (hi << 16);
      }
    }
  }
  __syncthreads();

  // ---- ctx = ksm^T @ v via MFMA: each wave owns a 64-row K-slice (2 k-steps of 32) ----
  floatx4 c2[9];
#pragma unroll
  for (int i = 0; i < 9; i++) c2[i] = z;
#pragma unroll
  for (int kk2 = 0; kk2 < 2; kk2++) {
    int rb = (wv << 6) + (kk2 << 5) + (quad << 3);
    short8 ak[3], av[3];
#pragma unroll
    for (int t = 0; t < 3; t++) {
      ak[t] = *(const short8*)&lkT[(t << 4) + l15][rb];
      av[t] = *(const short8*)&lvT[(t << 4) + l15][rb];
    }
#pragma unroll
    for (int dt = 0; dt < 3; dt++)
#pragma unroll
      for (int et = 0; et < 3; et++)
        c2[dt * 3 + et] = __builtin_amdgcn_mfma_f32_16x16x32_bf16(ak[dt], av[et], c2[dt * 3 + et], 0, 0, 0);
  }
  __syncthreads();   // done reading lkT/lvT; smem reused as pctx

  // ---- cross-wave reduce in LDS, then one atomicAdd per cell (as before) ----
#pragma unroll
  for (int dt = 0; dt < 3; dt++)
#pragma unroll
    for (int et = 0; et < 3; et++)
#pragma unroll
      for (int rr = 0; rr < 4; rr++) {
        int d = (dt << 4) + (quad << 2) + rr;
        int e = (et << 4) + l15;
        pctx[wv][d * 48 + e] = c2[dt * 3 + et][rr];
      }
  __syncthreads();
#pragma unroll
  for (int i = 0; i < 9; i++) {
    int cell = tid + (i << 8);
    float s = pctx[0][cell] + pctx[1][cell] + pctx[2][cell] + pctx[3][cell];
    atomicAdd(&ctx[(size_t)bh * 2304 + cell], s);
  }
}

// ---------------- Kernel 3: q GEMM tile + column sums of exp(q) -> S[b*384+col] -----------------
__global__ __launch_bounds__(256) void k_qsumk(
    const float* __restrict__ xa, const float* __restrict__ wqkv, float* __restrict__ S)
{
  const int bm = blockIdx.x;           // 512 row-tiles of 64
  const int b = bm >> 6;
  const int tid = threadIdx.x;
  const int wv = tid >> 6, lane = tid & 63, l15 = lane & 15, quad = lane >> 4;
  __shared__ __attribute__((aligned(16))) u16 lA[64][72];
  __shared__ __attribute__((aligned(16))) u16 lB[64][72];

  floatx4 acc[24];
  const floatx4 z = {0.f, 0.f, 0.f, 0.f};
#pragma unroll
  for (int i = 0; i < 24; i++) acc[i] = z;

  for (int k0 = 0; k0 < 384; k0 += 64) {
    __syncthreads();
#pragma unroll
    for (int i = 0; i < 4; i++) {
      int idx = tid + (i << 8);               // 0..1023
      int r = idx >> 4, c4 = (idx & 15) << 2;
      f4 v = *(const f4*)(xa + (size_t)((bm << 6) + r) * 384 + k0 + c4);
#pragma unroll
      for (int j = 0; j < 4; j++) lA[r][c4 + j] = f2bf(v[j]);
    }
    for (int ctg = 0; ctg < 6; ctg++) {
      __syncthreads();
#pragma unroll
      for (int i = 0; i < 4; i++) {
        int idx = tid + (i << 8);
        int r = idx >> 4, c4 = (idx & 15) << 2;    // r = k row, c4 = col offset
        f4 v = *(const f4*)(wqkv + (size_t)(k0 + r) * 1152 + (ctg << 6) + c4);
#pragma unroll
        for (int j = 0; j < 4; j++) lB[c4 + j][r] = f2bf(v[j]);
      }
      __syncthreads();
      int m = (wv << 4) + l15;
#pragma unroll
      for (int kk = 0; kk < 2; kk++) {
        short8 af = *(const short8*)&lA[m][(kk << 5) + (quad << 3)];
#pragma unroll
        for (int c4i = 0; c4i < 4; c4i++) {
          short8 bf = *(const short8*)&lB[(c4i << 4) + l15][(kk << 5) + (quad << 3)];
          acc[(ctg << 2) + c4i] = __builtin_amdgcn_mfma_f32_16x16x32_bf16(af, bf, acc[(ctg << 2) + c4i], 0, 0, 0);
        }
      }
    }
  }
#pragma unroll
  for (int t = 0; t < 24; t++) {
    float s = expf(acc[t][0]) + expf(acc[t][1]) + expf(acc[t][2]) + expf(acc[t][3]);
    s += __shfl_down(s, 32);
    s += __shfl_down(s, 16);
    if (lane < 16) atomicAdd(&S[b * 384 + (t << 4) + lane], s);
  }
}

// ---------------- Kernel 4: W2[b, h*48+d, c] = sum_e (ctx[bh,d,e]/S[..]) * wp[h*48+e, c] --------
// grid (64 bh, 3 coltiles of 128), block 256. LDS-staged, fully parallel.
__global__ __launch_bounds__(256) void k_w2(
    const float* __restrict__ ctx, const float* __restrict__ S,
    const float* __restrict__ wp, u16* __restrict__ W2)
{
  const int bh = blockIdx.x;   // 64
  const int b = bh >> 3, h = bh & 7;
  const int c0 = blockIdx.y << 7;
  const int tid = threadIdx.x;
  __shared__ float rs[48];
  __shared__ float c2[48][48];
  __shared__ float lwp[48][128];
  if (tid < 48) rs[tid] = 1.0f / S[b * 384 + h * 48 + tid];
  __syncthreads();
#pragma unroll
  for (int i = 0; i < 9; i++) {
    int cell = tid + (i << 8);
    int d = cell / 48, e = cell - d * 48;
    c2[d][e] = ctx[(size_t)bh * 2304 + cell] * rs[d];
  }
#pragma unroll
  for (int i = 0; i < 24; i++) {
    int idx = tid + (i << 8);            // 0..6143
    int e = idx >> 7, c = idx & 127;
    lwp[e][c] = wp[(size_t)(h * 48 + e) * 384 + c0 + c];
  }
  __syncthreads();
  const int c = tid & 127;
  const int dbase = tid >> 7;            // 0 or 1
#pragma unroll
  for (int it = 0; it < 24; it++) {
    int d = (it << 1) + dbase;
    float s = 0.f;
#pragma unroll
    for (int e = 0; e < 48; e++) s += c2[d][e] * lwp[e][c];
    W2[((size_t)b * 384 + h * 48 + d) * 384 + c0 + c] = f2bf(s);
  }
}

// ---------------- Kernel 5: out = exp(q_tile) @ W2_b + bias + x  (q recomputed in-block) --------
__global__ __launch_bounds__(256) void k_qproj(
    const float* __restrict__ xa, const float* __restrict__ wqkv, const u16* __restrict__ W2,
    const float* __restrict__ bias, const float* __restrict__ x, float* __restrict__ out)
{
  const int bm = blockIdx.x;           // 512 row-tiles of 64
  const int b = bm >> 6;
  const int tid = threadIdx.x;
  const int wv = tid >> 6, lane = tid & 63, l15 = lane & 15, quad = lane >> 4;
  __shared__ __attribute__((aligned(16))) u16 lA[64][72];
  __shared__ __attribute__((aligned(16))) u16 lB[64][72];
  __shared__ __attribute__((aligned(16))) u16 P[64][392];

  floatx4 acc[24];
  const floatx4 z = {0.f, 0.f, 0.f, 0.f};
#pragma unroll
  for (int i = 0; i < 24; i++) acc[i] = z;

  // phase 1: q = xa_rows @ wqkv[:, 0:384]
  for (int k0 = 0; k0 < 384; k0 += 64) {
    __syncthreads();
#pragma unroll
    for (int i = 0; i < 4; i++) {
      int idx = tid + (i << 8);
      int r = idx >> 4, c4 = (idx & 15) << 2;
      f4 v = *(const f4*)(xa + (size_t)((bm << 6) + r) * 384 + k0 + c4);
#pragma unroll
      for (int j = 0; j < 4; j++) lA[r][c4 + j] = f2bf(v[j]);
    }
    for (int ctg = 0; ctg < 6; ctg++) {
      __syncthreads();
#pragma unroll
      for (int i = 0; i < 4; i++) {
        int idx = tid + (i << 8);
        int r = idx >> 4, c4 = (idx & 15) << 2;
        f4 v = *(const f4*)(wqkv + (size_t)(k0 + r) * 1152 + (ctg << 6) + c4);
#pragma unroll
        for (int j = 0; j < 4; j++) lB[c4 + j][r] = f2bf(v[j]);
      }
      __syncthreads();
      int m = (wv << 4) + l15;
#pragma unroll
      for (int kk = 0; kk < 2; kk++) {
        short8 af = *(const short8*)&lA[m][(kk << 5) + (quad << 3)];
#pragma unroll
        for (int c4i = 0; c4i < 4; c4i++) {
          short8 bf = *(const short8*)&lB[(c4i << 4) + l15][(kk << 5) + (quad << 3)];
          acc[(ctg << 2) + c4i] = __builtin_amdgcn_mfma_f32_16x16x32_bf16(af, bf, acc[(ctg << 2) + c4i], 0, 0, 0);
        }
      }
    }
  }
  __syncthreads();
  // P = exp(q) in bf16
#pragma unroll
  for (int t = 0; t < 24; t++) {
    int col = (t << 4) + l15;
#pragma unroll
    for (int rr = 0; rr < 4; rr++) {
      int row = (wv << 4) + (quad << 2) + rr;
      P[row][col] = f2bf(expf(acc[t][rr]));
    }
  }
#pragma unroll
  for (int i = 0; i < 24; i++) acc[i] = z;
  __syncthreads();

  // phase 2: out_tile = P @ W2_b
  for (int k0 = 0; k0 < 384; k0 += 64) {
    for (int ctg = 0; ctg < 6; ctg++) {
      __syncthreads();
#pragma unroll
      for (int i = 0; i < 2; i++) {
        int idx = tid + (i << 8);
        int r = idx >> 3, c8 = (idx & 7) << 3;
        u16x8 v = *(const u16x8*)(W2 + ((size_t)b * 384 + k0 + r) * 384 + (ctg << 6) + c8);
#pragma unroll
        for (int j = 0; j < 8; j++) lB[c8 + j][r] = v[j];
      }
      __syncthreads();
      int m = (wv << 4) + l15;
#pragma unroll
      for (int kk = 0; kk < 2; kk++) {
        short8 af = *(const short8*)&P[m][k0 + (kk << 5) + (quad << 3)];
#pragma unroll
        for (int c4i = 0; c4i < 4; c4i++) {
          short8 bf = *(const short8*)&lB[(c4i << 4) + l15][(kk << 5) + (quad << 3)];
          acc[(ctg << 2) + c4i] = __builtin_amdgcn_mfma_f32_16x16x32_bf16(af, bf, acc[(ctg << 2) + c4i], 0, 0, 0);
        }
      }
    }
  }
  // epilogue: + bias + x, write out (own rows only -> in-place over xa is safe)
#pragma unroll
  for (int t = 0; t < 24; t++) {
    int col = (t << 4) + l15;
#pragma unroll
    for (int rr = 0; rr < 4; rr++) {
      int row = (bm << 6) + (wv << 4) + (quad << 2) + rr;
      float v = acc[t][rr] + bias[col] + x[(size_t)row * 384 + col];
      out[(size_t)row * 384 + col] = v;
    }
  }
}

extern "C" void kernel_launch(void* const* d_in, const int* in_sizes, int n_in,
                              void* d_out, int out_size, void* d_ws, size_t ws_size,
                              hipStream_t stream)
{
  const float* x      = (const float*)d_in[0];
  const float* w_sr   = (const float*)d_in[1];
  const float* b_sr   = (const float*)d_in[2];
  const float* ln_g   = (const float*)d_in[3];
  const float* ln_b   = (const float*)d_in[4];
  const float* w_qkv  = (const float*)d_in[5];
  const float* w_proj = (const float*)d_in[6];
  const float* b_proj = (const float*)d_in[7];
  float* out = (float*)d_out;

  // ws layout — total 2,961,408 bytes (~2.96 MB):
  //   [0,      12288)   S   [8][384] f32   (column sums of exp(q))
  //   [12288,  602112)  ctx [64][48][48] f32
  //   [602112, 2961408) W2  [8][384][384] bf16
  float* S   = (float*)d_ws;
  float* ctx = (float*)((char*)d_ws + 12288);
  u16*   W2  = (u16*)((char*)d_ws + 602112);
  float* xa  = out;   // conv result (f32) lives in d_out until k_qproj overwrites it row-locally

  hipMemsetAsync(d_ws, 0, 602112, stream);   // zero S + ctx

  k_conv_ln_gelu<<<BB * NN, CC, 0, stream>>>(x, w_sr, b_sr, ln_g, ln_b, xa);
  k_kvctx<<<dim3(128, 8), 256, 0, stream>>>(xa, w_qkv, ctx);
  k_qsumk<<<512, 256, 0, stream>>>(xa, w_qkv, S);
  k_w2<<<dim3(64, 3), 256, 0, stream>>>(ctx, S, w_proj, W2);
  k_qproj<<<512, 256, 0, stream>>>(xa, w_qkv, W2, b_proj, x, out);
}

// Round 2
// 433.398 us; speedup vs baseline: 1.6745x; 1.6745x over previous
//
#include <hip/hip_runtime.h>

typedef unsigned short u16;
typedef u16   u16x8  __attribute__((ext_vector_type(8)));
typedef short short8 __attribute__((ext_vector_type(8)));
typedef float floatx4 __attribute__((ext_vector_type(4)));
typedef float f4     __attribute__((ext_vector_type(4)));

#define BB 8
#define NN 4096
#define CC 384

__device__ __forceinline__ u16 f2bf(float f){
  unsigned u = __float_as_uint(f);
  u += 0x7FFFu + ((u >> 16) & 1u);   // round-to-nearest-even
  return (u16)(u >> 16);
}
__device__ __forceinline__ float bf2f(u16 u){ return __uint_as_float(((unsigned)u) << 16); }

// ---------------- Kernel 0: WT[col][k] = bf16(wqkv[k][col])  (1152 x 384, one-time transpose) ----
__global__ __launch_bounds__(256) void k_prep(const float* __restrict__ wqkv, u16* __restrict__ WT)
{
  const int cg = blockIdx.x % 18;        // 18 col-groups of 64
  const int kg = blockIdx.x / 18;        // 6 k-groups of 64
  const int c0 = cg << 6, k0 = kg << 6;
  const int tid = threadIdx.x;
  __shared__ u16 t[64][72];
#pragma unroll
  for (int i = 0; i < 4; i++) {
    int idx = tid + (i << 8);            // 0..1023
    int r = idx >> 4, c4 = (idx & 15) << 2;
    f4 v = *(const f4*)(wqkv + (size_t)(k0 + r) * 1152 + c0 + c4);
#pragma unroll
    for (int j = 0; j < 4; j++) t[c4 + j][r] = f2bf(v[j]);
  }
  __syncthreads();
#pragma unroll
  for (int i = 0; i < 2; i++) {
    int idx = tid + (i << 8);            // 0..511
    int c = idx >> 3, j = (idx & 7) << 3;
    *(u16x8*)(WT + (size_t)(c0 + c) * 384 + k0 + j) = *(const u16x8*)&t[c][j];
  }
}

// ---------------- Kernel 1: depthwise conv 3x3 + LayerNorm + GELU(erf) + residual -> xa16 (bf16) -
__global__ __launch_bounds__(384) void k_conv_ln_gelu(
    const float* __restrict__ x, const float* __restrict__ w_sr, const float* __restrict__ b_sr,
    const float* __restrict__ ln_g, const float* __restrict__ ln_b, u16* __restrict__ xa16)
{
  const int pix = blockIdx.x;            // b*4096 + n
  const int b = pix >> 12, n = pix & 4095;
  const int hh = n >> 6, ww = n & 63;
  const int c = threadIdx.x;

  float wgt[9];
#pragma unroll
  for (int i = 0; i < 9; i++) wgt[i] = w_sr[c * 9 + i];

  float acc = b_sr[c];
#pragma unroll
  for (int kh = 0; kh < 3; kh++) {
    int y = hh + kh - 1;
    if ((unsigned)y >= 64u) continue;
#pragma unroll
    for (int kw = 0; kw < 3; kw++) {
      int xx = ww + kw - 1;
      if ((unsigned)xx >= 64u) continue;
      acc += x[(((b << 12) + (y << 6) + xx) * CC) + c] * wgt[kh * 3 + kw];
    }
  }

  float s1 = acc, s2 = acc * acc;
#pragma unroll
  for (int o = 32; o > 0; o >>= 1) { s1 += __shfl_down(s1, o); s2 += __shfl_down(s2, o); }
  __shared__ float ls1[6], ls2[6], mb[2];
  const int wid = threadIdx.x >> 6, lane = threadIdx.x & 63;
  if (lane == 0) { ls1[wid] = s1; ls2[wid] = s2; }
  __syncthreads();
  if (threadIdx.x == 0) {
    float a = 0.f, q = 0.f;
#pragma unroll
    for (int i = 0; i < 6; i++) { a += ls1[i]; q += ls2[i]; }
    float mean = a * (1.0f / CC);
    float var  = q * (1.0f / CC) - mean * mean;
    mb[0] = mean; mb[1] = rsqrtf(var + 1e-5f);
  }
  __syncthreads();
  float xn = (acc - mb[0]) * mb[1] * ln_g[c] + ln_b[c];
  float g  = 0.5f * xn * (1.0f + erff(xn * 0.70710678118654752f));
  xa16[(size_t)pix * CC + c] = f2bf(x[(size_t)pix * CC + c] + g);
}

// ---------------- Kernel 2: fused k|v GEMM + register k-softmax + MFMA ctx ------------------------
// grid (128 rowtiles of 256, 8 heads), block 256. ctx[bh,48,48] += ksm^T @ v (MFMA, 48x48x256)
__global__ __launch_bounds__(256) void k_kvctx(
    const u16* __restrict__ xa16, const u16* __restrict__ WT, float* __restrict__ ctx)
{
  const int rt = blockIdx.x, h = blockIdx.y;
  const int n0 = rt << 8;
  const int bh = ((rt >> 4) << 3) + h;
  const int tid = threadIdx.x;
  const int wv = tid >> 6, lane = tid & 63, l15 = lane & 15, quad = lane >> 4;

  __shared__ __attribute__((aligned(16))) char smem[50688];
  u16 (*lA)[72]   = (u16(*)[72])smem;             // 256 x 72  (xa rows, k-chunk) bf16
  u16 (*lW)[72]   = (u16(*)[72])(smem + 36864);   // 96  x 72  (k|v cols of head h) bf16
  u16 (*lkT)[264] = (u16(*)[264])smem;            // 48 x 264  (ksm transposed: [d][r]) bf16
  u16 (*lvT)[264] = (u16(*)[264])(smem + 25344);  // 48 x 264  (v   transposed: [e][r]) bf16
  float (*pctx)[2304] = (float(*)[2304])smem;     // 4 x 2304  per-wave partial ctx

  floatx4 acc[24];
  const floatx4 z = {0.f, 0.f, 0.f, 0.f};
#pragma unroll
  for (int i = 0; i < 24; i++) acc[i] = z;

  for (int k0 = 0; k0 < 384; k0 += 64) {
    __syncthreads();
    // stage A: 256 rows x 64 k, pure bf16 vector copy
#pragma unroll
    for (int i = 0; i < 8; i++) {
      int idx = tid + (i << 8);               // 0..2047 chunks of 8
      int r = idx >> 3, c8 = (idx & 7) << 3;
      *(u16x8*)&lA[r][c8] = *(const u16x8*)(xa16 + (size_t)(n0 + r) * 384 + k0 + c8);
    }
    // stage W: 96 cols (k|v of head h) x 64 k, rows of WT are k-contiguous already
#pragma unroll
    for (int i = 0; i < 3; i++) {
      int idx = tid + (i << 8);               // 0..767 chunks of 8
      int c = idx >> 3, j = (idx & 7) << 3;
      int gcol = (c < 48) ? (384 + h * 48 + c) : (720 + h * 48 + c);
      *(u16x8*)&lW[c][j] = *(const u16x8*)(WT + (size_t)gcol * 384 + k0 + j);
    }
    __syncthreads();
#pragma unroll
    for (int rt4 = 0; rt4 < 4; rt4++) {
      int m = (wv << 6) + (rt4 << 4) + l15;
#pragma unroll
      for (int kk = 0; kk < 2; kk++) {
        short8 af = *(const short8*)&lA[m][(kk << 5) + (quad << 3)];
#pragma unroll
        for (int ct = 0; ct < 6; ct++) {
          short8 bf = *(const short8*)&lW[(ct << 4) + l15][(kk << 5) + (quad << 3)];
          acc[rt4 * 6 + ct] = __builtin_amdgcn_mfma_f32_16x16x32_bf16(af, bf, acc[rt4 * 6 + ct], 0, 0, 0);
        }
      }
    }
  }

  // ---- register softmax over the 48 k-columns of each row ----
#pragma unroll
  for (int rt4 = 0; rt4 < 4; rt4++) {
#pragma unroll
    for (int rr = 0; rr < 4; rr++) {
      float x0 = acc[rt4 * 6 + 0][rr];
      float x1 = acc[rt4 * 6 + 1][rr];
      float x2 = acc[rt4 * 6 + 2][rr];
      float m = fmaxf(fmaxf(x0, x1), x2);
#pragma unroll
      for (int o = 8; o >= 1; o >>= 1) m = fmaxf(m, __shfl_xor(m, o));
      float e0 = expf(x0 - m), e1 = expf(x1 - m), e2 = expf(x2 - m);
      float s = e0 + e1 + e2;
#pragma unroll
      for (int o = 8; o >= 1; o >>= 1) s += __shfl_xor(s, o);
      float inv = 1.0f / s;
      acc[rt4 * 6 + 0][rr] = e0 * inv;
      acc[rt4 * 6 + 1][rr] = e1 * inv;
      acc[rt4 * 6 + 2][rr] = e2 * inv;
    }
  }

  __syncthreads();   // all waves done reading lA/lW; smem reused as lkT/lvT

  // ---- store ksm^T and v^T (bf16, r-contiguous rows) for the ctx MFMA ----
#pragma unroll
  for (int rt4 = 0; rt4 < 4; rt4++) {
    int rowb = (wv << 6) + (rt4 << 4) + (quad << 2);
#pragma unroll
    for (int ct = 0; ct < 6; ct++) {
      int col = (ct << 4) + l15;
      u16 (*dst)[264] = (ct < 3) ? lkT : lvT;
      int c = (ct < 3) ? col : (col - 48);
#pragma unroll
      for (int rp = 0; rp < 2; rp++) {
        unsigned lo = f2bf(acc[rt4 * 6 + ct][(rp << 1) + 0]);
        unsigned hi = f2bf(acc[rt4 * 6 + ct][(rp << 1) + 1]);
        *(unsigned*)&dst[c][rowb + (rp << 1)] = lo | (hi << 16);
      }
    }
  }
  __syncthreads();

  // ---- ctx = ksm^T @ v via MFMA: each wave owns a 64-row K-slice (2 k-steps of 32) ----
  floatx4 c2[9];
#pragma unroll
  for (int i = 0; i < 9; i++) c2[i] = z;
#pragma unroll
  for (int kk2 = 0; kk2 < 2; kk2++) {
    int rb = (wv << 6) + (kk2 << 5) + (quad << 3);
    short8 ak[3], av[3];
#pragma unroll
    for (int t = 0; t < 3; t++) {
      ak[t] = *(const short8*)&lkT[(t << 4) + l15][rb];
      av[t] = *(const short8*)&lvT[(t << 4) + l15][rb];
    }
#pragma unroll
    for (int dt = 0; dt < 3; dt++)
#pragma unroll
      for (int et = 0; et < 3; et++)
        c2[dt * 3 + et] = __builtin_amdgcn_mfma_f32_16x16x32_bf16(ak[dt], av[et], c2[dt * 3 + et], 0, 0, 0);
  }
  __syncthreads();   // done reading lkT/lvT; smem reused as pctx

  // ---- cross-wave reduce in LDS, then one atomicAdd per cell ----
#pragma unroll
  for (int dt = 0; dt < 3; dt++)
#pragma unroll
    for (int et = 0; et < 3; et++)
#pragma unroll
      for (int rr = 0; rr < 4; rr++) {
        int d = (dt << 4) + (quad << 2) + rr;
        int e = (et << 4) + l15;
        pctx[wv][d * 48 + e] = c2[dt * 3 + et][rr];
      }
  __syncthreads();
#pragma unroll
  for (int i = 0; i < 9; i++) {
    int cell = tid + (i << 8);
    float s = pctx[0][cell] + pctx[1][cell] + pctx[2][cell] + pctx[3][cell];
    atomicAdd(&ctx[(size_t)bh * 2304 + cell], s);
  }
}

// ---------------- Kernel 3: q GEMM tile + column sums of exp(q) -> S[b*384+col] -----------------
__global__ __launch_bounds__(256) void k_qsumk(
    const u16* __restrict__ xa16, const u16* __restrict__ WT, float* __restrict__ S)
{
  const int bm = blockIdx.x;           // 512 row-tiles of 64
  const int b = bm >> 6;
  const int tid = threadIdx.x;
  const int wv = tid >> 6, lane = tid & 63, l15 = lane & 15, quad = lane >> 4;
  __shared__ __attribute__((aligned(16))) u16 lA[64][72];
  __shared__ __attribute__((aligned(16))) u16 lB[64][72];

  floatx4 acc[24];
  const floatx4 z = {0.f, 0.f, 0.f, 0.f};
#pragma unroll
  for (int i = 0; i < 24; i++) acc[i] = z;

  for (int k0 = 0; k0 < 384; k0 += 64) {
    __syncthreads();
#pragma unroll
    for (int i = 0; i < 2; i++) {
      int idx = tid + (i << 8);               // 0..511 chunks
      int r = idx >> 3, c8 = (idx & 7) << 3;
      *(u16x8*)&lA[r][c8] = *(const u16x8*)(xa16 + (size_t)((bm << 6) + r) * 384 + k0 + c8);
    }
    for (int ctg = 0; ctg < 6; ctg++) {
      __syncthreads();
#pragma unroll
      for (int i = 0; i < 2; i++) {
        int idx = tid + (i << 8);
        int c = idx >> 3, j = (idx & 7) << 3;
        *(u16x8*)&lB[c][j] = *(const u16x8*)(WT + (size_t)((ctg << 6) + c) * 384 + k0 + j);
      }
      __syncthreads();
      int m = (wv << 4) + l15;
#pragma unroll
      for (int kk = 0; kk < 2; kk++) {
        short8 af = *(const short8*)&lA[m][(kk << 5) + (quad << 3)];
#pragma unroll
        for (int c4i = 0; c4i < 4; c4i++) {
          short8 bf = *(const short8*)&lB[(c4i << 4) + l15][(kk << 5) + (quad << 3)];
          acc[(ctg << 2) + c4i] = __builtin_amdgcn_mfma_f32_16x16x32_bf16(af, bf, acc[(ctg << 2) + c4i], 0, 0, 0);
        }
      }
    }
  }
#pragma unroll
  for (int t = 0; t < 24; t++) {
    float s = expf(acc[t][0]) + expf(acc[t][1]) + expf(acc[t][2]) + expf(acc[t][3]);
    s += __shfl_down(s, 32);
    s += __shfl_down(s, 16);
    if (lane < 16) atomicAdd(&S[b * 384 + (t << 4) + lane], s);
  }
}

// ---------------- Kernel 4: W2T[b, c, h*48+d] = sum_e (ctx[bh,d,e]/S[..]) * wp[h*48+e, c] -------
// grid (64 bh, 3 coltiles of 128), block 256. Emits W2 TRANSPOSED (k-contiguous rows) in bf16.
__global__ __launch_bounds__(256) void k_w2(
    const float* __restrict__ ctx, const float* __restrict__ S,
    const float* __restrict__ wp, u16* __restrict__ W2T)
{
  const int bh = blockIdx.x;   // 64
  const int b = bh >> 3, h = bh & 7;
  const int c0 = blockIdx.y << 7;
  const int tid = threadIdx.x;
  __shared__ float rs[48];
  __shared__ float c2[48][48];
  __shared__ float lwp[48][128];
  __shared__ u16 tr[128][48];
  if (tid < 48) rs[tid] = 1.0f / S[b * 384 + h * 48 + tid];
  __syncthreads();
#pragma unroll
  for (int i = 0; i < 9; i++) {
    int cell = tid + (i << 8);
    int d = cell / 48, e = cell - d * 48;
    c2[d][e] = ctx[(size_t)bh * 2304 + cell] * rs[d];
  }
#pragma unroll
  for (int i = 0; i < 24; i++) {
    int idx = tid + (i << 8);            // 0..6143
    int e = idx >> 7, c = idx & 127;
    lwp[e][c] = wp[(size_t)(h * 48 + e) * 384 + c0 + c];
  }
  __syncthreads();
  const int c = tid & 127;
  const int dbase = tid >> 7;            // 0 or 1
#pragma unroll
  for (int it = 0; it < 24; it++) {
    int d = (it << 1) + dbase;
    float s = 0.f;
#pragma unroll
    for (int e = 0; e < 48; e++) s += c2[d][e] * lwp[e][c];
    tr[c][d] = f2bf(s);
  }
  __syncthreads();
  // write W2T rows: col-row (c0+c) gets its 48 (h,d) values k-contiguous; coalesced u16x8
  const int cc = tid >> 1, half = tid & 1;
#pragma unroll
  for (int i = 0; i < 3; i++) {
    u16x8 v = *(const u16x8*)&tr[cc][half * 24 + (i << 3)];
    *(u16x8*)(W2T + ((size_t)b * 384 + c0 + cc) * 384 + h * 48 + half * 24 + (i << 3)) = v;
  }
}

// ---------------- Kernel 5: out = exp(q_tile) @ W2_b + bias + x  (q recomputed in-block) --------
__global__ __launch_bounds__(256) void k_qproj(
    const u16* __restrict__ xa16, const u16* __restrict__ WT, const u16* __restrict__ W2T,
    const float* __restrict__ bias, const float* __restrict__ x, float* __restrict__ out)
{
  const int bm = blockIdx.x;           // 512 row-tiles of 64
  const int b = bm >> 6;
  const int tid = threadIdx.x;
  const int wv = tid >> 6, lane = tid & 63, l15 = lane & 15, quad = lane >> 4;
  __shared__ __attribute__((aligned(16))) u16 lA[64][72];
  __shared__ __attribute__((aligned(16))) u16 lB[64][72];
  __shared__ __attribute__((aligned(16))) u16 P[64][392];

  floatx4 acc[24];
  const floatx4 z = {0.f, 0.f, 0.f, 0.f};
#pragma unroll
  for (int i = 0; i < 24; i++) acc[i] = z;

  // phase 1: q = xa_rows @ wqkv[:, 0:384]  (A and B both bf16 vector copies now)
  for (int k0 = 0; k0 < 384; k0 += 64) {
    __syncthreads();
#pragma unroll
    for (int i = 0; i < 2; i++) {
      int idx = tid + (i << 8);
      int r = idx >> 3, c8 = (idx & 7) << 3;
      *(u16x8*)&lA[r][c8] = *(const u16x8*)(xa16 + (size_t)((bm << 6) + r) * 384 + k0 + c8);
    }
    for (int ctg = 0; ctg < 6; ctg++) {
      __syncthreads();
#pragma unroll
      for (int i = 0; i < 2; i++) {
        int idx = tid + (i << 8);
        int c = idx >> 3, j = (idx & 7) << 3;
        *(u16x8*)&lB[c][j] = *(const u16x8*)(WT + (size_t)((ctg << 6) + c) * 384 + k0 + j);
      }
      __syncthreads();
      int m = (wv << 4) + l15;
#pragma unroll
      for (int kk = 0; kk < 2; kk++) {
        short8 af = *(const short8*)&lA[m][(kk << 5) + (quad << 3)];
#pragma unroll
        for (int c4i = 0; c4i < 4; c4i++) {
          short8 bf = *(const short8*)&lB[(c4i << 4) + l15][(kk << 5) + (quad << 3)];
          acc[(ctg << 2) + c4i] = __builtin_amdgcn_mfma_f32_16x16x32_bf16(af, bf, acc[(ctg << 2) + c4i], 0, 0, 0);
        }
      }
    }
  }
  __syncthreads();
  // P = exp(q) in bf16
#pragma unroll
  for (int t = 0; t < 24; t++) {
    int col = (t << 4) + l15;
#pragma unroll
    for (int rr = 0; rr < 4; rr++) {
      int row = (wv << 4) + (quad << 2) + rr;
      P[row][col] = f2bf(expf(acc[t][rr]));
    }
  }
#pragma unroll
  for (int i = 0; i < 24; i++) acc[i] = z;
  __syncthreads();

  // phase 2: out_tile = P @ W2_b   (B from W2T, k-contiguous bf16 rows)
  for (int k0 = 0; k0 < 384; k0 += 64) {
    for (int ctg = 0; ctg < 6; ctg++) {
      __syncthreads();
#pragma unroll
      for (int i = 0; i < 2; i++) {
        int idx = tid + (i << 8);
        int c = idx >> 3, j = (idx & 7) << 3;
        *(u16x8*)&lB[c][j] = *(const u16x8*)(W2T + ((size_t)b * 384 + (ctg << 6) + c) * 384 + k0 + j);
      }
      __syncthreads();
      int m = (wv << 4) + l15;
#pragma unroll
      for (int kk = 0; kk < 2; kk++) {
        short8 af = *(const short8*)&P[m][k0 + (kk << 5) + (quad << 3)];
#pragma unroll
        for (int c4i = 0; c4i < 4; c4i++) {
          short8 bf = *(const short8*)&lB[(c4i << 4) + l15][(kk << 5) + (quad << 3)];
          acc[(ctg << 2) + c4i] = __builtin_amdgcn_mfma_f32_16x16x32_bf16(af, bf, acc[(ctg << 2) + c4i], 0, 0, 0);
        }
      }
    }
  }
  // epilogue: + bias + x, write out
#pragma unroll
  for (int t = 0; t < 24; t++) {
    int col = (t << 4) + l15;
#pragma unroll
    for (int rr = 0; rr < 4; rr++) {
      int row = (bm << 6) + (wv << 4) + (quad << 2) + rr;
      float v = acc[t][rr] + bias[col] + x[(size_t)row * 384 + col];
      out[(size_t)row * 384 + col] = v;
    }
  }
}

extern "C" void kernel_launch(void* const* d_in, const int* in_sizes, int n_in,
                              void* d_out, int out_size, void* d_ws, size_t ws_size,
                              hipStream_t stream)
{
  const float* x      = (const float*)d_in[0];
  const float* w_sr   = (const float*)d_in[1];
  const float* b_sr   = (const float*)d_in[2];
  const float* ln_g   = (const float*)d_in[3];
  const float* ln_b   = (const float*)d_in[4];
  const float* w_qkv  = (const float*)d_in[5];
  const float* w_proj = (const float*)d_in[6];
  const float* b_proj = (const float*)d_in[7];
  float* out = (float*)d_out;

  // ws layout — total 29,011,968 bytes (~29 MB):
  //   [0,        12288)     S    [8][384] f32      (column sums of exp(q))
  //   [12288,    602112)    ctx  [64][48][48] f32
  //   [602112,   1486848)   WT   [1152][384] bf16  (w_qkv transposed, k-contiguous)
  //   [1486848,  3846144)   W2T  [8][384][384] bf16 (ctx/S @ w_proj, transposed)
  //   [3846144,  29011968)  xa16 [32768][384] bf16 (conv+LN+GELU+residual output)
  float* S   = (float*)d_ws;
  float* ctx = (float*)((char*)d_ws + 12288);
  u16*   WT  = (u16*)((char*)d_ws + 602112);
  u16*   W2T = (u16*)((char*)d_ws + 1486848);
  u16*   xa16= (u16*)((char*)d_ws + 3846144);

  hipMemsetAsync(d_ws, 0, 602112, stream);   // zero S + ctx

  k_prep<<<108, 256, 0, stream>>>(w_qkv, WT);
  k_conv_ln_gelu<<<BB * NN, CC, 0, stream>>>(x, w_sr, b_sr, ln_g, ln_b, xa16);
  k_kvctx<<<dim3(128, 8), 256, 0, stream>>>(xa16, WT, ctx);
  k_qsumk<<<512, 256, 0, stream>>>(xa16, WT, S);
  k_w2<<<dim3(64, 3), 256, 0, stream>>>(ctx, S, w_proj, W2T);
  k_qproj<<<512, 256, 0, stream>>>(xa16, WT, W2T, b_proj, x, out);
}

// Round 3
// 297.761 us; speedup vs baseline: 2.4373x; 1.4555x over previous
//
#include <hip/hip_runtime.h>

typedef unsigned short u16;
typedef u16   u16x8  __attribute__((ext_vector_type(8)));
typedef short short8 __attribute__((ext_vector_type(8)));
typedef float floatx4 __attribute__((ext_vector_type(4)));
typedef float f4     __attribute__((ext_vector_type(4)));

#define BB 8
#define NN 4096
#define CC 384

__device__ __forceinline__ u16 f2bf(float f){
  unsigned u = __float_as_uint(f);
  u += 0x7FFFu + ((u >> 16) & 1u);   // round-to-nearest-even
  return (u16)(u >> 16);
}
__device__ __forceinline__ float bf2f(u16 u){ return __uint_as_float(((unsigned)u) << 16); }

// ---------------- Kernel 0: WT[col][k] = bf16(wqkv[k][col])  (1152 x 384, one-time transpose) ----
__global__ __launch_bounds__(256) void k_prep(const float* __restrict__ wqkv, u16* __restrict__ WT)
{
  const int cg = blockIdx.x % 18;        // 18 col-groups of 64
  const int kg = blockIdx.x / 18;        // 6 k-groups of 64
  const int c0 = cg << 6, k0 = kg << 6;
  const int tid = threadIdx.x;
  __shared__ u16 t[64][72];
#pragma unroll
  for (int i = 0; i < 4; i++) {
    int idx = tid + (i << 8);            // 0..1023
    int r = idx >> 4, c4 = (idx & 15) << 2;
    f4 v = *(const f4*)(wqkv + (size_t)(k0 + r) * 1152 + c0 + c4);
#pragma unroll
    for (int j = 0; j < 4; j++) t[c4 + j][r] = f2bf(v[j]);
  }
  __syncthreads();
#pragma unroll
  for (int i = 0; i < 2; i++) {
    int idx = tid + (i << 8);            // 0..511
    int c = idx >> 3, j = (idx & 7) << 3;
    *(u16x8*)(WT + (size_t)(c0 + c) * 384 + k0 + j) = *(const u16x8*)&t[c][j];
  }
}

// ---------------- Kernel 1: depthwise conv 3x3 + LN + GELU(erf) + residual -> xa16 (bf16) -------
// block = 8 consecutive pixels in one image row x 384 channels. Register sliding window:
// 3x10 taps loaded once per thread, shared across the 8 pixels; all 8 LN reduces batched.
__global__ __launch_bounds__(384) void k_conv_ln_gelu(
    const float* __restrict__ x, const float* __restrict__ w_sr, const float* __restrict__ b_sr,
    const float* __restrict__ ln_g, const float* __restrict__ ln_b, u16* __restrict__ xa16)
{
  const int blk = blockIdx.x;          // b*512 + hh*8 + wg
  const int b = blk >> 9;
  const int hh = (blk >> 3) & 63;
  const int ww0 = (blk & 7) << 3;      // pixels ww0..ww0+7
  const int c = threadIdx.x;

  float wgt[9];
#pragma unroll
  for (int i = 0; i < 9; i++) wgt[i] = w_sr[c * 9 + i];
  const float lg = ln_g[c], lb = ln_b[c];
  const float bias = b_sr[c];

  // 3 rows x 10 cols window, zero-padded at image borders (issued upfront, independent)
  float rowv[3][10];
#pragma unroll
  for (int r = 0; r < 3; r++) {
    int y = hh + r - 1;
    bool yok = (unsigned)y < 64u;
#pragma unroll
    for (int j = 0; j < 10; j++) {
      int xx = ww0 + j - 1;
      bool ok = yok && ((unsigned)xx < 64u);
      rowv[r][j] = ok ? x[((size_t)((b << 12) + (y << 6) + xx)) * CC + c] : 0.f;
    }
  }

  float acc[8];
#pragma unroll
  for (int p = 0; p < 8; p++) {
    float a = bias;
#pragma unroll
    for (int r = 0; r < 3; r++)
#pragma unroll
      for (int j = 0; j < 3; j++)
        a += rowv[r][p + j] * wgt[r * 3 + j];
    acc[p] = a;
  }

  __shared__ float ls1[6][8], ls2[6][8], mb[2][8];
  const int wid = threadIdx.x >> 6, lane = threadIdx.x & 63;
#pragma unroll
  for (int p = 0; p < 8; p++) {
    float s1 = acc[p], s2 = acc[p] * acc[p];
#pragma unroll
    for (int o = 32; o > 0; o >>= 1) { s1 += __shfl_down(s1, o); s2 += __shfl_down(s2, o); }
    if (lane == 0) { ls1[wid][p] = s1; ls2[wid][p] = s2; }
  }
  __syncthreads();
  if (threadIdx.x < 8) {
    int p = threadIdx.x;
    float a = 0.f, q = 0.f;
#pragma unroll
    for (int i = 0; i < 6; i++) { a += ls1[i][p]; q += ls2[i][p]; }
    float mean = a * (1.0f / CC);
    float var  = q * (1.0f / CC) - mean * mean;
    mb[0][p] = mean; mb[1][p] = rsqrtf(var + 1e-5f);
  }
  __syncthreads();
#pragma unroll
  for (int p = 0; p < 8; p++) {
    float xn = (acc[p] - mb[0][p]) * mb[1][p] * lg + lb;
    float g  = 0.5f * xn * (1.0f + erff(xn * 0.70710678118654752f));
    size_t pix = (size_t)(b << 12) + (hh << 6) + ww0 + p;
    xa16[pix * CC + c] = f2bf(rowv[1][p + 1] + g);   // center tap doubles as residual
  }
}

// ---------------- Kernel 2: fused k|v GEMM + register k-softmax + MFMA ctx ------------------------
// grid (128 rowtiles of 256, 8 heads), block 256. ctx[bh,48,48] += ksm^T @ v (MFMA, 48x48x256)
__global__ __launch_bounds__(256) void k_kvctx(
    const u16* __restrict__ xa16, const u16* __restrict__ WT, float* __restrict__ ctx)
{
  const int rt = blockIdx.x, h = blockIdx.y;
  const int n0 = rt << 8;
  const int bh = ((rt >> 4) << 3) + h;
  const int tid = threadIdx.x;
  const int wv = tid >> 6, lane = tid & 63, l15 = lane & 15, quad = lane >> 4;

  __shared__ __attribute__((aligned(16))) char smem[50688];
  u16 (*lA)[72]   = (u16(*)[72])smem;             // 256 x 72  (xa rows, k-chunk) bf16
  u16 (*lW)[72]   = (u16(*)[72])(smem + 36864);   // 96  x 72  (k|v cols of head h) bf16
  u16 (*lkT)[264] = (u16(*)[264])smem;            // 48 x 264  (ksm transposed: [d][r]) bf16
  u16 (*lvT)[264] = (u16(*)[264])(smem + 25344);  // 48 x 264  (v   transposed: [e][r]) bf16
  float (*pctx)[2304] = (float(*)[2304])smem;     // 4 x 2304  per-wave partial ctx

  floatx4 acc[24];
  const floatx4 z = {0.f, 0.f, 0.f, 0.f};
#pragma unroll
  for (int i = 0; i < 24; i++) acc[i] = z;

  for (int k0 = 0; k0 < 384; k0 += 64) {
    __syncthreads();
    // stage A: 256 rows x 64 k, pure bf16 vector copy
#pragma unroll
    for (int i = 0; i < 8; i++) {
      int idx = tid + (i << 8);               // 0..2047 chunks of 8
      int r = idx >> 3, c8 = (idx & 7) << 3;
      *(u16x8*)&lA[r][c8] = *(const u16x8*)(xa16 + (size_t)(n0 + r) * 384 + k0 + c8);
    }
    // stage W: 96 cols (k|v of head h) x 64 k, rows of WT are k-contiguous already
#pragma unroll
    for (int i = 0; i < 3; i++) {
      int idx = tid + (i << 8);               // 0..767 chunks of 8
      int c = idx >> 3, j = (idx & 7) << 3;
      int gcol = (c < 48) ? (384 + h * 48 + c) : (720 + h * 48 + c);
      *(u16x8*)&lW[c][j] = *(const u16x8*)(WT + (size_t)gcol * 384 + k0 + j);
    }
    __syncthreads();
#pragma unroll
    for (int rt4 = 0; rt4 < 4; rt4++) {
      int m = (wv << 6) + (rt4 << 4) + l15;
#pragma unroll
      for (int kk = 0; kk < 2; kk++) {
        short8 af = *(const short8*)&lA[m][(kk << 5) + (quad << 3)];
#pragma unroll
        for (int ct = 0; ct < 6; ct++) {
          short8 bf = *(const short8*)&lW[(ct << 4) + l15][(kk << 5) + (quad << 3)];
          acc[rt4 * 6 + ct] = __builtin_amdgcn_mfma_f32_16x16x32_bf16(af, bf, acc[rt4 * 6 + ct], 0, 0, 0);
        }
      }
    }
  }

  // ---- register softmax over the 48 k-columns of each row ----
#pragma unroll
  for (int rt4 = 0; rt4 < 4; rt4++) {
#pragma unroll
    for (int rr = 0; rr < 4; rr++) {
      float x0 = acc[rt4 * 6 + 0][rr];
      float x1 = acc[rt4 * 6 + 1][rr];
      float x2 = acc[rt4 * 6 + 2][rr];
      float m = fmaxf(fmaxf(x0, x1), x2);
#pragma unroll
      for (int o = 8; o >= 1; o >>= 1) m = fmaxf(m, __shfl_xor(m, o));
      float e0 = expf(x0 - m), e1 = expf(x1 - m), e2 = expf(x2 - m);
      float s = e0 + e1 + e2;
#pragma unroll
      for (int o = 8; o >= 1; o >>= 1) s += __shfl_xor(s, o);
      float inv = 1.0f / s;
      acc[rt4 * 6 + 0][rr] = e0 * inv;
      acc[rt4 * 6 + 1][rr] = e1 * inv;
      acc[rt4 * 6 + 2][rr] = e2 * inv;
    }
  }

  __syncthreads();   // all waves done reading lA/lW; smem reused as lkT/lvT

  // ---- store ksm^T and v^T (bf16, r-contiguous rows) for the ctx MFMA ----
#pragma unroll
  for (int rt4 = 0; rt4 < 4; rt4++) {
    int rowb = (wv << 6) + (rt4 << 4) + (quad << 2);
#pragma unroll
    for (int ct = 0; ct < 6; ct++) {
      int col = (ct << 4) + l15;
      u16 (*dst)[264] = (ct < 3) ? lkT : lvT;
      int c = (ct < 3) ? col : (col - 48);
#pragma unroll
      for (int rp = 0; rp < 2; rp++) {
        unsigned lo = f2bf(acc[rt4 * 6 + ct][(rp << 1) + 0]);
        unsigned hi = f2bf(acc[rt4 * 6 + ct][(rp << 1) + 1]);
        *(unsigned*)&dst[c][rowb + (rp << 1)] = lo | (hi << 16);
      }
    }
  }
  __syncthreads();

  // ---- ctx = ksm^T @ v via MFMA: each wave owns a 64-row K-slice (2 k-steps of 32) ----
  floatx4 c2[9];
#pragma unroll
  for (int i = 0; i < 9; i++) c2[i] = z;
#pragma unroll
  for (int kk2 = 0; kk2 < 2; kk2++) {
    int rb = (wv << 6) + (kk2 << 5) + (quad << 3);
    short8 ak[3], av[3];
#pragma unroll
    for (int t = 0; t < 3; t++) {
      ak[t] = *(const short8*)&lkT[(t << 4) + l15][rb];
      av[t] = *(const short8*)&lvT[(t << 4) + l15][rb];
    }
#pragma unroll
    for (int dt = 0; dt < 3; dt++)
#pragma unroll
      for (int et = 0; et < 3; et++)
        c2[dt * 3 + et] = __builtin_amdgcn_mfma_f32_16x16x32_bf16(ak[dt], av[et], c2[dt * 3 + et], 0, 0, 0);
  }
  __syncthreads();   // done reading lkT/lvT; smem reused as pctx

  // ---- cross-wave reduce in LDS, then one atomicAdd per cell ----
#pragma unroll
  for (int dt = 0; dt < 3; dt++)
#pragma unroll
    for (int et = 0; et < 3; et++)
#pragma unroll
      for (int rr = 0; rr < 4; rr++) {
        int d = (dt << 4) + (quad << 2) + rr;
        int e = (et << 4) + l15;
        pctx[wv][d * 48 + e] = c2[dt * 3 + et][rr];
      }
  __syncthreads();
#pragma unroll
  for (int i = 0; i < 9; i++) {
    int cell = tid + (i << 8);
    float s = pctx[0][cell] + pctx[1][cell] + pctx[2][cell] + pctx[3][cell];
    atomicAdd(&ctx[(size_t)bh * 2304 + cell], s);
  }
}

// ---------------- Kernel 3: q GEMM + col sums of exp(q) -> S; stores P16=bf16(exp(q)) ------------
// P16 is written IN PLACE over xa16 (each block reads/writes only its own 64-row tile;
// all xa16 reads complete before the epilogue stores).
__global__ __launch_bounds__(256) void k_qsumk(
    const u16* __restrict__ xa16, const u16* __restrict__ WT, float* __restrict__ S,
    u16* __restrict__ P16)
{
  const int bm = blockIdx.x;           // 512 row-tiles of 64
  const int b = bm >> 6;
  const int tid = threadIdx.x;
  const int wv = tid >> 6, lane = tid & 63, l15 = lane & 15, quad = lane >> 4;
  __shared__ __attribute__((aligned(16))) u16 lA[64][72];
  __shared__ __attribute__((aligned(16))) u16 lB[64][72];

  floatx4 acc[24];
  const floatx4 z = {0.f, 0.f, 0.f, 0.f};
#pragma unroll
  for (int i = 0; i < 24; i++) acc[i] = z;

  for (int k0 = 0; k0 < 384; k0 += 64) {
    __syncthreads();
#pragma unroll
    for (int i = 0; i < 2; i++) {
      int idx = tid + (i << 8);               // 0..511 chunks
      int r = idx >> 3, c8 = (idx & 7) << 3;
      *(u16x8*)&lA[r][c8] = *(const u16x8*)(xa16 + (size_t)((bm << 6) + r) * 384 + k0 + c8);
    }
    for (int ctg = 0; ctg < 6; ctg++) {
      __syncthreads();
#pragma unroll
      for (int i = 0; i < 2; i++) {
        int idx = tid + (i << 8);
        int c = idx >> 3, j = (idx & 7) << 3;
        *(u16x8*)&lB[c][j] = *(const u16x8*)(WT + (size_t)((ctg << 6) + c) * 384 + k0 + j);
      }
      __syncthreads();
      int m = (wv << 4) + l15;
#pragma unroll
      for (int kk = 0; kk < 2; kk++) {
        short8 af = *(const short8*)&lA[m][(kk << 5) + (quad << 3)];
#pragma unroll
        for (int c4i = 0; c4i < 4; c4i++) {
          short8 bf = *(const short8*)&lB[(c4i << 4) + l15][(kk << 5) + (quad << 3)];
          acc[(ctg << 2) + c4i] = __builtin_amdgcn_mfma_f32_16x16x32_bf16(af, bf, acc[(ctg << 2) + c4i], 0, 0, 0);
        }
      }
    }
  }
#pragma unroll
  for (int t = 0; t < 24; t++) {
    int col = (t << 4) + l15;
    float e0 = expf(acc[t][0]), e1 = expf(acc[t][1]), e2 = expf(acc[t][2]), e3 = expf(acc[t][3]);
    int rowb = (bm << 6) + (wv << 4) + (quad << 2);
    P16[(size_t)(rowb + 0) * 384 + col] = f2bf(e0);
    P16[(size_t)(rowb + 1) * 384 + col] = f2bf(e1);
    P16[(size_t)(rowb + 2) * 384 + col] = f2bf(e2);
    P16[(size_t)(rowb + 3) * 384 + col] = f2bf(e3);
    float s = e0 + e1 + e2 + e3;
    s += __shfl_down(s, 32);
    s += __shfl_down(s, 16);
    if (lane < 16) atomicAdd(&S[b * 384 + (t << 4) + lane], s);
  }
}

// ---------------- Kernel 4: W2T[b, c, h*48+d] = sum_e (ctx[bh,d,e]/S[..]) * wp[h*48+e, c] -------
__global__ __launch_bounds__(256) void k_w2(
    const float* __restrict__ ctx, const float* __restrict__ S,
    const float* __restrict__ wp, u16* __restrict__ W2T)
{
  const int bh = blockIdx.x;   // 64
  const int b = bh >> 3, h = bh & 7;
  const int c0 = blockIdx.y << 7;
  const int tid = threadIdx.x;
  __shared__ float rs[48];
  __shared__ float c2[48][48];
  __shared__ float lwp[48][128];
  __shared__ u16 tr[128][48];
  if (tid < 48) rs[tid] = 1.0f / S[b * 384 + h * 48 + tid];
  __syncthreads();
#pragma unroll
  for (int i = 0; i < 9; i++) {
    int cell = tid + (i << 8);
    int d = cell / 48, e = cell - d * 48;
    c2[d][e] = ctx[(size_t)bh * 2304 + cell] * rs[d];
  }
#pragma unroll
  for (int i = 0; i < 24; i++) {
    int idx = tid + (i << 8);            // 0..6143
    int e = idx >> 7, c = idx & 127;
    lwp[e][c] = wp[(size_t)(h * 48 + e) * 384 + c0 + c];
  }
  __syncthreads();
  const int c = tid & 127;
  const int dbase = tid >> 7;            // 0 or 1
#pragma unroll
  for (int it = 0; it < 24; it++) {
    int d = (it << 1) + dbase;
    float s = 0.f;
#pragma unroll
    for (int e = 0; e < 48; e++) s += c2[d][e] * lwp[e][c];
    tr[c][d] = f2bf(s);
  }
  __syncthreads();
  const int cc = tid >> 1, half = tid & 1;
#pragma unroll
  for (int i = 0; i < 3; i++) {
    u16x8 v = *(const u16x8*)&tr[cc][half * 24 + (i << 3)];
    *(u16x8*)(W2T + ((size_t)b * 384 + c0 + cc) * 384 + h * 48 + half * 24 + (i << 3)) = v;
  }
}

// ---------------- Kernel 5: out = P_tile @ W2_b + bias + x  (P precomputed by k_qsumk) ----------
__global__ __launch_bounds__(256) void k_qproj(
    const u16* __restrict__ P16, const u16* __restrict__ W2T,
    const float* __restrict__ bias, const float* __restrict__ x, float* __restrict__ out)
{
  const int bm = blockIdx.x;           // 512 row-tiles of 64
  const int b = bm >> 6;
  const int tid = threadIdx.x;
  const int wv = tid >> 6, lane = tid & 63, l15 = lane & 15, quad = lane >> 4;
  __shared__ __attribute__((aligned(16))) u16 lB[64][72];
  __shared__ __attribute__((aligned(16))) u16 P[64][392];

  floatx4 acc[24];
  const floatx4 z = {0.f, 0.f, 0.f, 0.f};
#pragma unroll
  for (int i = 0; i < 24; i++) acc[i] = z;

  // load own P tile (64 rows x 384) straight into LDS
#pragma unroll
  for (int i = 0; i < 12; i++) {
    int idx = tid + (i << 8);            // 0..3071 chunks of 8
    int r = idx / 48, ch = idx - r * 48, j = ch << 3;
    *(u16x8*)&P[r][j] = *(const u16x8*)(P16 + (size_t)((bm << 6) + r) * 384 + j);
  }

  for (int k0 = 0; k0 < 384; k0 += 64) {
    for (int ctg = 0; ctg < 6; ctg++) {
      __syncthreads();
#pragma unroll
      for (int i = 0; i < 2; i++) {
        int idx = tid + (i << 8);
        int c = idx >> 3, j = (idx & 7) << 3;
        *(u16x8*)&lB[c][j] = *(const u16x8*)(W2T + ((size_t)b * 384 + (ctg << 6) + c) * 384 + k0 + j);
      }
      __syncthreads();
      int m = (wv << 4) + l15;
#pragma unroll
      for (int kk = 0; kk < 2; kk++) {
        short8 af = *(const short8*)&P[m][k0 + (kk << 5) + (quad << 3)];
#pragma unroll
        for (int c4i = 0; c4i < 4; c4i++) {
          short8 bf = *(const short8*)&lB[(c4i << 4) + l15][(kk << 5) + (quad << 3)];
          acc[(ctg << 2) + c4i] = __builtin_amdgcn_mfma_f32_16x16x32_bf16(af, bf, acc[(ctg << 2) + c4i], 0, 0, 0);
        }
      }
    }
  }
  // epilogue: + bias + x, write out
#pragma unroll
  for (int t = 0; t < 24; t++) {
    int col = (t << 4) + l15;
#pragma unroll
    for (int rr = 0; rr < 4; rr++) {
      int row = (bm << 6) + (wv << 4) + (quad << 2) + rr;
      float v = acc[t][rr] + bias[col] + x[(size_t)row * 384 + col];
      out[(size_t)row * 384 + col] = v;
    }
  }
}

extern "C" void kernel_launch(void* const* d_in, const int* in_sizes, int n_in,
                              void* d_out, int out_size, void* d_ws, size_t ws_size,
                              hipStream_t stream)
{
  const float* x      = (const float*)d_in[0];
  const float* w_sr   = (const float*)d_in[1];
  const float* b_sr   = (const float*)d_in[2];
  const float* ln_g   = (const float*)d_in[3];
  const float* ln_b   = (const float*)d_in[4];
  const float* w_qkv  = (const float*)d_in[5];
  const float* w_proj = (const float*)d_in[6];
  const float* b_proj = (const float*)d_in[7];
  float* out = (float*)d_out;

  // ws layout — total 29,011,968 bytes (~29 MB):
  //   [0,        12288)     S    [8][384] f32
  //   [12288,    602112)    ctx  [64][48][48] f32
  //   [602112,   1486848)   WT   [1152][384] bf16
  //   [1486848,  3846144)   W2T  [8][384][384] bf16
  //   [3846144,  29011968)  xa16 [32768][384] bf16  (overwritten in-place by P16=bf16(exp(q)))
  float* S   = (float*)d_ws;
  float* ctx = (float*)((char*)d_ws + 12288);
  u16*   WT  = (u16*)((char*)d_ws + 602112);
  u16*   W2T = (u16*)((char*)d_ws + 1486848);
  u16*   xa16= (u16*)((char*)d_ws + 3846144);
  u16*   P16 = xa16;   // in-place: k_qsumk overwrites its own rows after last read

  hipMemsetAsync(d_ws, 0, 602112, stream);   // zero S + ctx

  k_prep<<<108, 256, 0, stream>>>(w_qkv, WT);
  k_conv_ln_gelu<<<BB * 512, 384, 0, stream>>>(x, w_sr, b_sr, ln_g, ln_b, xa16);
  k_kvctx<<<dim3(128, 8), 256, 0, stream>>>(xa16, WT, ctx);
  k_qsumk<<<512, 256, 0, stream>>>(xa16, WT, S, P16);
  k_w2<<<dim3(64, 3), 256, 0, stream>>>(ctx, S, w_proj, W2T);
  k_qproj<<<512, 256, 0, stream>>>(P16, W2T, b_proj, x, out);
}